// Round 7
// baseline (427.679 us; speedup 1.0000x reference)
//
#include <hip/hip_runtime.h>
#include <hip/hip_bf16.h>
#include <math.h>

#define S_TOTAL 7681

typedef __attribute__((ext_vector_type(8))) short bf16x8;
typedef __attribute__((ext_vector_type(4))) float f32x4;

// fp32 -> bf16 round-to-nearest-even
__device__ __forceinline__ short f2b(float x) {
    union { float f; unsigned u; } v; v.f = x;
    unsigned r = v.u + 0x7FFFu + ((v.u >> 16) & 1u);
    return (short)(r >> 16);
}
__device__ __forceinline__ float b2f(unsigned short u) {
    union { unsigned u; float f; } t; t.u = ((unsigned)u) << 16; return t.f;
}

// async global->LDS, 16B/lane. LDS dest: wave-uniform base + lane*16 (linear).
__device__ __forceinline__ void gll16(const short* g, short* l) {
    __builtin_amdgcn_global_load_lds(
        (const __attribute__((address_space(1))) unsigned int*)g,
        (__attribute__((address_space(3))) unsigned int*)l,
        16, 0, 0);
}

// raw barrier: no compiler-inserted vmcnt(0) drain (unlike __syncthreads)
#define SBAR() asm volatile("s_barrier" ::: "memory")

#define MFMA16(a, b, c) __builtin_amdgcn_mfma_f32_16x16x32_bf16(a, b, c, 0, 0, 0)

// ---------------------------------------------------------------------------
// Weight transpose + convert (W[K][N] fp32 -> Wt[N][K] bf16), PLUS the
// src/pos cvt_copy folded into the same dispatch (blocks t >= 736).
// grid = (736 + 641, 1, 3)
// ---------------------------------------------------------------------------
__global__ __launch_bounds__(256) void transpose_cvt_kernel(
    const float* __restrict__ s0, const float* __restrict__ s1,
    const float* __restrict__ s2, const float* __restrict__ s3,
    const float* __restrict__ s4, const float* __restrict__ s5,
    short* __restrict__ d0, short* __restrict__ d1, short* __restrict__ d2,
    short* __restrict__ d3, short* __restrict__ d4, short* __restrict__ d5,
    const float4* __restrict__ csrc, const float4* __restrict__ cpos,
    float4* __restrict__ co, ushort4* __restrict__ cxb, ushort4* __restrict__ cqb)
{
    const int z = blockIdx.z;
    int t = blockIdx.x;
    if (t >= 736) {
        const int n4 = S_TOTAL * 64;
        int i = (z * 641 + (t - 736)) * 256 + threadIdx.x;
        if (i < n4) {
            float4 v = csrc[i], p = cpos[i];
            co[i] = v;
            ushort4 h, hq;
            h.x = (unsigned short)f2b(v.x); h.y = (unsigned short)f2b(v.y);
            h.z = (unsigned short)f2b(v.z); h.w = (unsigned short)f2b(v.w);
            hq.x = (unsigned short)f2b(v.x + p.x); hq.y = (unsigned short)f2b(v.y + p.y);
            hq.z = (unsigned short)f2b(v.z + p.z); hq.w = (unsigned short)f2b(v.w + p.w);
            cxb[i] = h;
            cqb[i] = hq;
        }
        return;
    }
    const float* src; short* dst; int K, N, lt;
    if (t < 64)       { src = s0 + (size_t)z * 65536;  dst = d0 + (size_t)z * 65536;  K = 256;  N = 256;  lt = t; }
    else if (t < 128) { src = s1 + (size_t)z * 65536;  dst = d1 + (size_t)z * 98304;  K = 256;  N = 256;  lt = t - 64; }
    else if (t < 160) { src = s2 + (size_t)z * 32768;  dst = d2 + (size_t)z * 98304;  K = 256;  N = 128;  lt = t - 128; }
    else if (t < 224) { src = s3 + (size_t)z * 65536;  dst = d3 + (size_t)z * 65536;  K = 256;  N = 256;  lt = t - 160; }
    else if (t < 480) { src = s4 + (size_t)z * 262144; dst = d4 + (size_t)z * 262144; K = 256;  N = 1024; lt = t - 224; }
    else              { src = s5 + (size_t)z * 262144; dst = d5 + (size_t)z * 262144; K = 1024; N = 256;  lt = t - 480; }
    const int ntx = N >> 5;
    const int tk = (lt / ntx) << 5, tn = (lt % ntx) << 5;
    __shared__ float tile[32][33];
    const int cx = threadIdx.x & 31, cy = threadIdx.x >> 5;
    #pragma unroll
    for (int i = 0; i < 32; i += 8)
        tile[cy + i][cx] = src[(size_t)(tk + cy + i) * N + tn + cx];
    __syncthreads();
    #pragma unroll
    for (int i = 0; i < 32; i += 8)
        dst[(size_t)(tn + cy + i) * K + tk + cx] = f2b(tile[cx][cy + i]);
}

// ---------------------------------------------------------------------------
// Merged value + off/attn GEMM (K=256), 128x64 tile, BK=64, gll staging,
// counted vmcnt, both-sides XOR swizzle (r4-verified). grid (61, 10).
// ---------------------------------------------------------------------------
__global__ __launch_bounds__(256) void gemm_va_kernel(
    const short* __restrict__ xb, const short* __restrict__ qb,
    const short* __restrict__ Wt_val, const short* __restrict__ Wt_oa,
    const float* __restrict__ b_val, const float* __restrict__ b_off,
    const float* __restrict__ b_attn,
    short* __restrict__ value_bf, float* __restrict__ offbuf, int M)
{
    const int grp = (blockIdx.y >= 4);
    const short* A  = grp ? qb : xb;
    const short* Wt = grp ? Wt_oa : Wt_val;
    const int colBase = (grp ? (blockIdx.y - 4) : blockIdx.y) * 64;
    const int K = 256;

    __shared__ __align__(16) short As[2][128 * 64];
    __shared__ __align__(16) short Bs[2][64 * 64];

    const int tid = threadIdx.x;
    const int lane = tid & 63;
    const int wave = tid >> 6;
    const int rowBase = blockIdx.x * 128;

    const int sr = lane >> 3;
    const int sc = ((lane & 7) ^ sr) << 3;

    const short* gA[4];
    #pragma unroll
    for (int c = 0; c < 4; ++c)
        gA[c] = A + (size_t)min(rowBase + wave * 32 + c * 8 + sr, M - 1) * K + sc;
    const short* gB[2];
    #pragma unroll
    for (int c = 0; c < 2; ++c)
        gB[c] = Wt + (size_t)(colBase + wave * 16 + c * 8 + sr) * K + sc;

    const int frow = lane & 15;
    const int g4 = lane >> 4;
    const int r7 = frow & 7;
    const int wm = wave * 32;

    f32x4 acc[2][4] = {};

    auto stage = [&](int buf, int k0) {
        #pragma unroll
        for (int c = 0; c < 4; ++c)
            gll16(gA[c] + k0, &As[buf][(wave * 32 + c * 8) * 64]);
        #pragma unroll
        for (int c = 0; c < 2; ++c)
            gll16(gB[c] + k0, &Bs[buf][(wave * 16 + c * 8) * 64]);
    };

    stage(0, 0);

    int cur = 0;
    for (int k0 = 0; k0 < K; k0 += 64) {
        if (k0 + 64 < K) {
            stage(cur ^ 1, k0 + 64);
            asm volatile("s_waitcnt vmcnt(6)" ::: "memory");
        } else {
            asm volatile("s_waitcnt vmcnt(0)" ::: "memory");
        }
        SBAR();
        #pragma unroll
        for (int kk8 = 0; kk8 < 8; kk8 += 4) {
            const int ua = (((kk8 + g4) ^ r7) << 3);
            bf16x8 af0 = *(const bf16x8*)&As[cur][(wm + frow) * 64 + ua];
            bf16x8 af1 = *(const bf16x8*)&As[cur][(wm + 16 + frow) * 64 + ua];
            #pragma unroll
            for (int j = 0; j < 4; ++j) {
                bf16x8 bfj = *(const bf16x8*)&Bs[cur][(j * 16 + frow) * 64 + ua];
                acc[0][j] = MFMA16(af0, bfj, acc[0][j]);
                acc[1][j] = MFMA16(af1, bfj, acc[1][j]);
            }
        }
        SBAR();
        cur ^= 1;
    }

    const int erow = (lane >> 4) * 4;
    const int ecol = lane & 15;
    #pragma unroll
    for (int mi = 0; mi < 2; ++mi) {
        #pragma unroll
        for (int j = 0; j < 4; ++j) {
            int col = colBase + j * 16 + ecol;
            float bias = grp ? (col < 256 ? b_off[col] : b_attn[col - 256]) : b_val[col];
            #pragma unroll
            for (int r = 0; r < 4; ++r) {
                int row = rowBase + wm + mi * 16 + erow + r;
                if (row < M) {
                    float v = acc[mi][j][r] + bias;
                    if (grp) offbuf[(size_t)row * 384 + col] = v;
                    else     value_bf[(size_t)row * 256 + col] = f2b(v);
                }
            }
        }
    }
}

// ---------------------------------------------------------------------------
// Plain GEMM + bias (+relu) (+residual add), 128x64 tile, BK=64, gll staging,
// counted vmcnt, both-sides XOR swizzle (r4-verified structure).
//  RELU: relu epilogue.  OUTBF: bf16 output (else fp32).  RESID: += resid.
// Used: out-proj  <0,0,1> grid (61,4)  (msdab@Wout + b + out -> tmp fp32)
//       ff1       <1,1,0> grid (61,16) (xb@W1 + b, relu -> hid bf16)
//       ff2       <0,0,1> grid (61,4)  (hid@W2 + b + out -> tmp fp32)
// ---------------------------------------------------------------------------
template<int RELU, int OUTBF, int RESID>
__global__ __launch_bounds__(256) void gemm_kernel(
    const short* __restrict__ A, const short* __restrict__ Wt,
    const float* __restrict__ bias, const float* __restrict__ resid,
    void* __restrict__ Cv, int M, int N, int K)
{
    __shared__ __align__(16) short As[2][128 * 64];
    __shared__ __align__(16) short Bs[2][64 * 64];

    const int tid = threadIdx.x;
    const int lane = tid & 63;
    const int wave = tid >> 6;
    const int rowBase = blockIdx.x * 128;
    const int colBase = blockIdx.y * 64;

    const int sr = lane >> 3;
    const int sc = ((lane & 7) ^ sr) << 3;

    const short* gA[4];
    #pragma unroll
    for (int c = 0; c < 4; ++c)
        gA[c] = A + (size_t)min(rowBase + wave * 32 + c * 8 + sr, M - 1) * K + sc;
    const short* gB[2];
    #pragma unroll
    for (int c = 0; c < 2; ++c)
        gB[c] = Wt + (size_t)(colBase + wave * 16 + c * 8 + sr) * K + sc;

    const int frow = lane & 15;
    const int g4 = lane >> 4;
    const int r7 = frow & 7;
    const int wm = wave * 32;

    f32x4 acc[2][4] = {};

    auto stage = [&](int buf, int k0) {
        #pragma unroll
        for (int c = 0; c < 4; ++c)
            gll16(gA[c] + k0, &As[buf][(wave * 32 + c * 8) * 64]);
        #pragma unroll
        for (int c = 0; c < 2; ++c)
            gll16(gB[c] + k0, &Bs[buf][(wave * 16 + c * 8) * 64]);
    };

    stage(0, 0);

    int cur = 0;
    for (int k0 = 0; k0 < K; k0 += 64) {
        if (k0 + 64 < K) {
            stage(cur ^ 1, k0 + 64);
            asm volatile("s_waitcnt vmcnt(6)" ::: "memory");
        } else {
            asm volatile("s_waitcnt vmcnt(0)" ::: "memory");
        }
        SBAR();
        #pragma unroll
        for (int kk8 = 0; kk8 < 8; kk8 += 4) {
            const int ua = (((kk8 + g4) ^ r7) << 3);
            bf16x8 af0 = *(const bf16x8*)&As[cur][(wm + frow) * 64 + ua];
            bf16x8 af1 = *(const bf16x8*)&As[cur][(wm + 16 + frow) * 64 + ua];
            #pragma unroll
            for (int j = 0; j < 4; ++j) {
                bf16x8 bfj = *(const bf16x8*)&Bs[cur][(j * 16 + frow) * 64 + ua];
                acc[0][j] = MFMA16(af0, bfj, acc[0][j]);
                acc[1][j] = MFMA16(af1, bfj, acc[1][j]);
            }
        }
        SBAR();
        cur ^= 1;
    }

    const int erow = (lane >> 4) * 4;
    const int ecol = lane & 15;
    #pragma unroll
    for (int mi = 0; mi < 2; ++mi) {
        #pragma unroll
        for (int j = 0; j < 4; ++j) {
            #pragma unroll
            for (int r = 0; r < 4; ++r) {
                int row = rowBase + wm + mi * 16 + erow + r;
                if (row < M) {
                    int col = colBase + j * 16 + ecol;
                    float v = acc[mi][j][r] + bias[col];
                    if (RESID) v += resid[(size_t)row * N + col];
                    if (RELU) v = fmaxf(v, 0.f);
                    if (OUTBF) ((short*)Cv)[(size_t)row * N + col] = f2b(v);
                    else       ((float*)Cv)[(size_t)row * N + col] = v;
                }
            }
        }
    }
}

// ---------------------------------------------------------------------------
// LayerNorm over 256 cols, 1 wave per row (4 rows/block), float4 lanes.
// reads tmp fp32; writes out fp32, xb = bf16(y), (WRITEQ) qb = bf16(y + pos).
// grid = ceil(M/4). Memory-bound streaming pass.
// ---------------------------------------------------------------------------
template<int WRITEQ>
__global__ __launch_bounds__(256) void ln_kernel(
    const float4* __restrict__ tmp, const float4* __restrict__ g4v,
    const float4* __restrict__ b4v, const float4* __restrict__ pos,
    float4* __restrict__ out, ushort4* __restrict__ xb, ushort4* __restrict__ qb,
    int M)
{
    const int lane = threadIdx.x & 63;
    const int row = blockIdx.x * 4 + (threadIdx.x >> 6);
    if (row >= M) return;
    const size_t idx = (size_t)row * 64 + lane;

    float4 v = tmp[idx];
    float s1 = v.x + v.y + v.z + v.w;
    float s2 = v.x * v.x + v.y * v.y + v.z * v.z + v.w * v.w;
    #pragma unroll
    for (int o = 1; o < 64; o <<= 1) {
        s1 += __shfl_xor(s1, o);
        s2 += __shfl_xor(s2, o);
    }
    float mu = s1 * (1.f / 256.f);
    float rs = rsqrtf(s2 * (1.f / 256.f) - mu * mu + 1e-5f);

    float4 gg = g4v[lane], bb = b4v[lane];
    float4 y;
    y.x = (v.x - mu) * rs * gg.x + bb.x;
    y.y = (v.y - mu) * rs * gg.y + bb.y;
    y.z = (v.z - mu) * rs * gg.z + bb.z;
    y.w = (v.w - mu) * rs * gg.w + bb.w;

    out[idx] = y;
    ushort4 h;
    h.x = (unsigned short)f2b(y.x); h.y = (unsigned short)f2b(y.y);
    h.z = (unsigned short)f2b(y.z); h.w = (unsigned short)f2b(y.w);
    xb[idx] = h;
    if (WRITEQ) {
        float4 p = pos[idx];
        ushort4 hq;
        hq.x = (unsigned short)f2b(y.x + p.x); hq.y = (unsigned short)f2b(y.y + p.y);
        hq.z = (unsigned short)f2b(y.z + p.z); hq.w = (unsigned short)f2b(y.w + p.w);
        qb[idx] = hq;
    }
}

// ---------------------------------------------------------------------------
// MSDA sampling v4 (unchanged). grid = 968 = 8*121
// ---------------------------------------------------------------------------
__global__ __launch_bounds__(256) void msda_kernel(
    const short* __restrict__ value, const float* __restrict__ offb,
    short* __restrict__ msdab)
{
    __shared__ float   soff[8 * 384];
    __shared__ ushort4 sIdx[1024];
    __shared__ float4  sWgt[1024];

    const int bid = blockIdx.x;
    const int sb = (bid & 7) * 121 + (bid >> 3);
    const int q0 = sb * 8;
    if (q0 >= S_TOTAL) return;
    const int tid = threadIdx.x;

    {
        const float4* src4 = (const float4*)offb;
        #pragma unroll
        for (int i = tid; i < 768; i += 256) {
            int qi = i / 96, j = i - qi * 96;
            int q = min(q0 + qi, S_TOTAL - 1);
            *(float4*)&soff[qi * 384 + j * 4] = src4[(size_t)q * 96 + j];
        }
    }
    __syncthreads();

    if (tid < 64) {
        const int qi = tid >> 3, m = tid & 7;
        float* lg = &soff[qi * 384 + 256 + m * 16];
        float mx = -1e30f;
        #pragma unroll
        for (int k = 0; k < 16; ++k) mx = fmaxf(mx, lg[k]);
        float e[16], sum = 0.f;
        #pragma unroll
        for (int k = 0; k < 16; ++k) { e[k] = expf(lg[k] - mx); sum += e[k]; }
        float inv = 1.f / sum;
        #pragma unroll
        for (int k = 0; k < 16; ++k) lg[k] = e[k] * inv;
    }
    __syncthreads();

    #pragma unroll
    for (int it = tid; it < 1024; it += 256) {
        const int qi = it >> 7, i = it & 127;
        const int lvl = (i >> 2) & 3;
        const int q = min(q0 + qi, S_TOTAL - 1);

        float refx, refy;
        if (q < 5776)      { int t = q;        int r = t / 76, c = t % 76; refx = (c + 0.5f) / 76.f; refy = (r + 0.5f) / 76.f; }
        else if (q < 7220) { int t = q - 5776; int r = t / 38, c = t % 38; refx = (c + 0.5f) / 38.f; refy = (r + 0.5f) / 38.f; }
        else if (q < 7581) { int t = q - 7220; int r = t / 19, c = t % 19; refx = (c + 0.5f) / 19.f; refy = (r + 0.5f) / 19.f; }
        else               { int t = q - 7581; int r = t / 10, c = t % 10; refx = (c + 0.5f) / 10.f; refy = (r + 0.5f) / 10.f; }

        const int LVL_HW[4] = {76, 38, 19, 10};
        const int LVL_ST[4] = {0, 5776, 7220, 7581};
        const int W = LVL_HW[lvl];
        const float fW = (float)W;

        float ox = soff[qi * 384 + i * 2];
        float oy = soff[qi * 384 + i * 2 + 1];
        float aw = soff[qi * 384 + 256 + i];

        float x = refx * fW + ox - 0.5f;
        float y = refy * fW + oy - 0.5f;
        float x0f = floorf(x), y0f = floorf(y);
        int x0 = (int)x0f, y0 = (int)y0f;
        float dx = x - x0f, dy = y - y0f;

        bool vx0 = (x0 >= 0) & (x0 < W);
        bool vx1 = (x0 >= -1) & (x0 < W - 1);
        bool vy0 = (y0 >= 0) & (y0 < W);
        bool vy1 = (y0 >= -1) & (y0 < W - 1);
        int xc0 = min(max(x0, 0), W - 1), xc1 = min(max(x0 + 1, 0), W - 1);
        int yc0 = min(max(y0, 0), W - 1), yc1 = min(max(y0 + 1, 0), W - 1);
        int base = LVL_ST[lvl];
        ushort4 id;
        id.x = (unsigned short)(base + yc0 * W + xc0);
        id.y = (unsigned short)(base + yc0 * W + xc1);
        id.z = (unsigned short)(base + yc1 * W + xc0);
        id.w = (unsigned short)(base + yc1 * W + xc1);
        float4 w4;
        w4.x = (vy0 && vx0) ? (1.f - dy) * (1.f - dx) * aw : 0.f;
        w4.y = (vy0 && vx1) ? (1.f - dy) * dx * aw : 0.f;
        w4.z = (vy1 && vx0) ? dy * (1.f - dx) * aw : 0.f;
        w4.w = (vy1 && vx1) ? dy * dx * aw : 0.f;
        sIdx[it] = id;
        sWgt[it] = w4;
    }
    __syncthreads();

    const int lane = tid & 63;
    const int qi = (tid >> 6) * 2 + (lane >> 5);
    const int q = q0 + qi;
    if (q >= S_TOTAL) return;
    const int l32 = lane & 31;
    const int h = l32 >> 2, dg = l32 & 3;
    const short* vcol = value + h * 32 + dg * 8;
    const int itb = qi * 128 + (h << 4);

    float a[8] = {};
    #pragma unroll
    for (int pt = 0; pt < 16; ++pt) {
        const ushort4 id = sIdx[itb + pt];
        const float4 w = sWgt[itb + pt];
        bf16x8 v0 = *(const bf16x8*)(vcol + ((size_t)id.x << 8));
        bf16x8 v1 = *(const bf16x8*)(vcol + ((size_t)id.y << 8));
        bf16x8 v2 = *(const bf16x8*)(vcol + ((size_t)id.z << 8));
        bf16x8 v3 = *(const bf16x8*)(vcol + ((size_t)id.w << 8));
        #pragma unroll
        for (int e = 0; e < 8; ++e)
            a[e] += w.x * b2f((unsigned short)v0[e]) + w.y * b2f((unsigned short)v1[e])
                  + w.z * b2f((unsigned short)v2[e]) + w.w * b2f((unsigned short)v3[e]);
    }
    bf16x8 o;
    #pragma unroll
    for (int e = 0; e < 8; ++e) o[e] = f2b(a[e]);
    *(bf16x8*)(msdab + (size_t)q * 256 + h * 32 + dg * 8) = o;
}

// ---------------------------------------------------------------------------
extern "C" void kernel_launch(void* const* d_in, const int* in_sizes, int n_in,
                              void* d_out, int out_size, void* d_ws, size_t ws_size,
                              hipStream_t stream) {
    const float* src    = (const float*)d_in[0];
    const float* pos    = (const float*)d_in[1];
    const float* W_off  = (const float*)d_in[6];
    const float* b_off  = (const float*)d_in[7];
    const float* W_attn = (const float*)d_in[8];
    const float* b_attn = (const float*)d_in[9];
    const float* W_val  = (const float*)d_in[10];
    const float* b_val  = (const float*)d_in[11];
    const float* W_out  = (const float*)d_in[12];
    const float* b_out  = (const float*)d_in[13];
    const float* ln1_g  = (const float*)d_in[14];
    const float* ln1_b  = (const float*)d_in[15];
    const float* W_ff1  = (const float*)d_in[16];
    const float* b_ff1  = (const float*)d_in[17];
    const float* W_ff2  = (const float*)d_in[18];
    const float* b_ff2  = (const float*)d_in[19];
    const float* ln2_g  = (const float*)d_in[20];
    const float* ln2_b  = (const float*)d_in[21];

    const size_t S = S_TOTAL;
    float* out = (float*)d_out;

    // --- workspace layout ---
    short* wt = (short*)d_ws;
    short* Wt_val = wt;             // 3 x [256][256]
    short* Wt_oa  = wt + 196608;    // 3 x [384][256]
    short* Wt_out = wt + 491520;    // 3 x [256][256]
    short* Wt_ff1 = wt + 688128;    // 3 x [1024][256]
    short* Wt_ff2 = wt + 1474560;   // 3 x [256][1024]
    float* fbase  = (float*)d_ws + 1131648;
    short* xb       = (short*)fbase;               // [S][256] bf16
    short* qb       = (short*)(fbase + 128 * S);   // [S][256] bf16
    short* value_bf = (short*)(fbase + 256 * S);   // [S][256] bf16
    float* offb     = fbase + 384 * S;             // [S][384] fp32
    short* msdab    = (short*)(fbase + 768 * S);   // [S][256] bf16
    float* tmp      = fbase + 896 * S;             // [S][256] fp32
    short* hid      = (short*)(fbase + 256 * S);   // [S][1024] bf16 (FFN phase; overlaps value+offb)

    transpose_cvt_kernel<<<dim3(1377, 1, 3), 256, 0, stream>>>(
        W_val, W_off, W_attn, W_out, W_ff1, W_ff2,
        Wt_val, Wt_oa, Wt_oa + 65536, Wt_out, Wt_ff1, Wt_ff2,
        (const float4*)src, (const float4*)pos,
        (float4*)out, (ushort4*)xb, (ushort4*)qb);

    const int MB = (S_TOTAL + 127) / 128;     // 61
    const int LNB = (S_TOTAL + 3) / 4;        // 1921

    for (int l = 0; l < 3; ++l) {
        // value (bf16) + off/attn (fp32) in one dispatch
        gemm_va_kernel<<<dim3(MB, 10), 256, 0, stream>>>(
            xb, qb, Wt_val + (size_t)l * 65536, Wt_oa + (size_t)l * 98304,
            b_val + (size_t)l * 256, b_off + (size_t)l * 256, b_attn + (size_t)l * 128,
            value_bf, offb, S_TOTAL);
        // sampling -> bf16
        msda_kernel<<<968, 256, 0, stream>>>(value_bf, offb, msdab);
        // tmp = msdab @ Wout + b_out + out   (efficient 128x64 tiles)
        gemm_kernel<0, 0, 1><<<dim3(MB, 4), 256, 0, stream>>>(
            msdab, Wt_out + (size_t)l * 65536, b_out + (size_t)l * 256,
            out, tmp, S_TOTAL, 256, 256);
        // out = LN1(tmp); xb = bf16(out)
        ln_kernel<0><<<LNB, 256, 0, stream>>>(
            (const float4*)tmp, (const float4*)(ln1_g + (size_t)l * 256),
            (const float4*)(ln1_b + (size_t)l * 256), (const float4*)pos,
            (float4*)out, (ushort4*)xb, (ushort4*)qb, S_TOTAL);
        // hid = bf16(relu(xb @ Wff1 + b))
        gemm_kernel<1, 1, 0><<<dim3(MB, 16), 256, 0, stream>>>(
            xb, Wt_ff1 + (size_t)l * 262144, b_ff1 + (size_t)l * 1024,
            nullptr, hid, S_TOTAL, 1024, 256);
        // tmp = hid @ Wff2 + b_ff2 + out
        gemm_kernel<0, 0, 1><<<dim3(MB, 4), 256, 0, stream>>>(
            hid, Wt_ff2 + (size_t)l * 262144, b_ff2 + (size_t)l * 256,
            out, tmp, S_TOTAL, 256, 1024);
        // out = LN2(tmp); xb, qb for next layer
        ln_kernel<1><<<LNB, 256, 0, stream>>>(
            (const float4*)tmp, (const float4*)(ln2_g + (size_t)l * 256),
            (const float4*)(ln2_b + (size_t)l * 256), (const float4*)pos,
            (float4*)out, (ushort4*)xb, (ushort4*)qb, S_TOTAL);
    }
}

// Round 8
// 388.265 us; speedup vs baseline: 1.1015x; 1.1015x over previous
//
#include <hip/hip_runtime.h>
#include <hip/hip_bf16.h>
#include <math.h>

#define S_TOTAL 7681

typedef __attribute__((ext_vector_type(8))) short bf16x8;
typedef __attribute__((ext_vector_type(4))) float f32x4;

// fp32 -> bf16 round-to-nearest-even
__device__ __forceinline__ short f2b(float x) {
    union { float f; unsigned u; } v; v.f = x;
    unsigned r = v.u + 0x7FFFu + ((v.u >> 16) & 1u);
    return (short)(r >> 16);
}
__device__ __forceinline__ float b2f(unsigned short u) {
    union { unsigned u; float f; } t; t.u = ((unsigned)u) << 16; return t.f;
}

// async global->LDS, 16B/lane. LDS dest: wave-uniform base + lane*16 (linear).
__device__ __forceinline__ void gll16(const short* g, short* l) {
    __builtin_amdgcn_global_load_lds(
        (const __attribute__((address_space(1))) unsigned int*)g,
        (__attribute__((address_space(3))) unsigned int*)l,
        16, 0, 0);
}

// raw barrier: no compiler-inserted vmcnt(0) drain (unlike __syncthreads)
#define SBAR() asm volatile("s_barrier" ::: "memory")

#define MFMA16(a, b, c) __builtin_amdgcn_mfma_f32_16x16x32_bf16(a, b, c, 0, 0, 0)

// ---------------------------------------------------------------------------
// Weight transpose + convert (W[K][N] fp32 -> Wt[N][K] bf16), PLUS the
// src/pos cvt_copy folded into the same dispatch (blocks t >= 736).
// grid = (736 + 641, 1, 3)
// ---------------------------------------------------------------------------
__global__ __launch_bounds__(256) void transpose_cvt_kernel(
    const float* __restrict__ s0, const float* __restrict__ s1,
    const float* __restrict__ s2, const float* __restrict__ s3,
    const float* __restrict__ s4, const float* __restrict__ s5,
    short* __restrict__ d0, short* __restrict__ d1, short* __restrict__ d2,
    short* __restrict__ d3, short* __restrict__ d4, short* __restrict__ d5,
    const float4* __restrict__ csrc, const float4* __restrict__ cpos,
    float4* __restrict__ co, ushort4* __restrict__ cxb, ushort4* __restrict__ cqb)
{
    const int z = blockIdx.z;
    int t = blockIdx.x;
    if (t >= 736) {
        // cvt_copy part: out = src; xb = bf16(src); qb = bf16(src + pos)
        const int n4 = S_TOTAL * 64;
        int i = (z * 641 + (t - 736)) * 256 + threadIdx.x;
        if (i < n4) {
            float4 v = csrc[i], p = cpos[i];
            co[i] = v;
            ushort4 h, hq;
            h.x = (unsigned short)f2b(v.x); h.y = (unsigned short)f2b(v.y);
            h.z = (unsigned short)f2b(v.z); h.w = (unsigned short)f2b(v.w);
            hq.x = (unsigned short)f2b(v.x + p.x); hq.y = (unsigned short)f2b(v.y + p.y);
            hq.z = (unsigned short)f2b(v.z + p.z); hq.w = (unsigned short)f2b(v.w + p.w);
            cxb[i] = h;
            cqb[i] = hq;
        }
        return;
    }
    const float* src; short* dst; int K, N, lt;
    if (t < 64)       { src = s0 + (size_t)z * 65536;  dst = d0 + (size_t)z * 65536;  K = 256;  N = 256;  lt = t; }
    else if (t < 128) { src = s1 + (size_t)z * 65536;  dst = d1 + (size_t)z * 98304;  K = 256;  N = 256;  lt = t - 64; }
    else if (t < 160) { src = s2 + (size_t)z * 32768;  dst = d2 + (size_t)z * 98304;  K = 256;  N = 128;  lt = t - 128; }
    else if (t < 224) { src = s3 + (size_t)z * 65536;  dst = d3 + (size_t)z * 65536;  K = 256;  N = 256;  lt = t - 160; }
    else if (t < 480) { src = s4 + (size_t)z * 262144; dst = d4 + (size_t)z * 262144; K = 256;  N = 1024; lt = t - 224; }
    else              { src = s5 + (size_t)z * 262144; dst = d5 + (size_t)z * 262144; K = 1024; N = 256;  lt = t - 480; }
    const int ntx = N >> 5;
    const int tk = (lt / ntx) << 5, tn = (lt % ntx) << 5;
    __shared__ float tile[32][33];
    const int cx = threadIdx.x & 31, cy = threadIdx.x >> 5;
    #pragma unroll
    for (int i = 0; i < 32; i += 8)
        tile[cy + i][cx] = src[(size_t)(tk + cy + i) * N + tn + cx];
    __syncthreads();
    #pragma unroll
    for (int i = 0; i < 32; i += 8)
        dst[(size_t)(tn + cy + i) * K + tk + cx] = f2b(tile[cx][cy + i]);
}

// ---------------------------------------------------------------------------
// Merged value + off/attn GEMM (K=256), 128x64 tile, BK=64, gll staging,
// counted vmcnt, both-sides XOR swizzle (r4-verified). grid (61, 10).
// ---------------------------------------------------------------------------
__global__ __launch_bounds__(256) void gemm_va_kernel(
    const short* __restrict__ xb, const short* __restrict__ qb,
    const short* __restrict__ Wt_val, const short* __restrict__ Wt_oa,
    const float* __restrict__ b_val, const float* __restrict__ b_off,
    const float* __restrict__ b_attn,
    short* __restrict__ value_bf, float* __restrict__ offbuf, int M)
{
    const int grp = (blockIdx.y >= 4);
    const short* A  = grp ? qb : xb;
    const short* Wt = grp ? Wt_oa : Wt_val;
    const int colBase = (grp ? (blockIdx.y - 4) : blockIdx.y) * 64;
    const int K = 256;

    __shared__ __align__(16) short As[2][128 * 64];
    __shared__ __align__(16) short Bs[2][64 * 64];

    const int tid = threadIdx.x;
    const int lane = tid & 63;
    const int wave = tid >> 6;
    const int rowBase = blockIdx.x * 128;

    const int sr = lane >> 3;
    const int sc = ((lane & 7) ^ sr) << 3;

    const short* gA[4];
    #pragma unroll
    for (int c = 0; c < 4; ++c)
        gA[c] = A + (size_t)min(rowBase + wave * 32 + c * 8 + sr, M - 1) * K + sc;
    const short* gB[2];
    #pragma unroll
    for (int c = 0; c < 2; ++c)
        gB[c] = Wt + (size_t)(colBase + wave * 16 + c * 8 + sr) * K + sc;

    const int frow = lane & 15;
    const int g4 = lane >> 4;
    const int r7 = frow & 7;
    const int wm = wave * 32;

    f32x4 acc[2][4] = {};

    auto stage = [&](int buf, int k0) {
        #pragma unroll
        for (int c = 0; c < 4; ++c)
            gll16(gA[c] + k0, &As[buf][(wave * 32 + c * 8) * 64]);
        #pragma unroll
        for (int c = 0; c < 2; ++c)
            gll16(gB[c] + k0, &Bs[buf][(wave * 16 + c * 8) * 64]);
    };

    stage(0, 0);

    int cur = 0;
    for (int k0 = 0; k0 < K; k0 += 64) {
        if (k0 + 64 < K) {
            stage(cur ^ 1, k0 + 64);
            asm volatile("s_waitcnt vmcnt(6)" ::: "memory");
        } else {
            asm volatile("s_waitcnt vmcnt(0)" ::: "memory");
        }
        SBAR();
        #pragma unroll
        for (int kk8 = 0; kk8 < 8; kk8 += 4) {
            const int ua = (((kk8 + g4) ^ r7) << 3);
            bf16x8 af0 = *(const bf16x8*)&As[cur][(wm + frow) * 64 + ua];
            bf16x8 af1 = *(const bf16x8*)&As[cur][(wm + 16 + frow) * 64 + ua];
            #pragma unroll
            for (int j = 0; j < 4; ++j) {
                bf16x8 bfj = *(const bf16x8*)&Bs[cur][(j * 16 + frow) * 64 + ua];
                acc[0][j] = MFMA16(af0, bfj, acc[0][j]);
                acc[1][j] = MFMA16(af1, bfj, acc[1][j]);
            }
        }
        SBAR();
        cur ^= 1;
    }

    const int erow = (lane >> 4) * 4;
    const int ecol = lane & 15;
    #pragma unroll
    for (int mi = 0; mi < 2; ++mi) {
        #pragma unroll
        for (int j = 0; j < 4; ++j) {
            int col = colBase + j * 16 + ecol;
            float bias = grp ? (col < 256 ? b_off[col] : b_attn[col - 256]) : b_val[col];
            #pragma unroll
            for (int r = 0; r < 4; ++r) {
                int row = rowBase + wm + mi * 16 + erow + r;
                if (row < M) {
                    float v = acc[mi][j][r] + bias;
                    if (grp) offbuf[(size_t)row * 384 + col] = v;
                    else     value_bf[(size_t)row * 256 + col] = f2b(v);
                }
            }
        }
    }
}

// ---------------------------------------------------------------------------
// Plain GEMM + bias (+relu). Used for ff1 (M=7681, N=1024, K=256).
// r4-verified.
// ---------------------------------------------------------------------------
template<int RELU, int OUTBF>
__global__ __launch_bounds__(256) void gemm_kernel(
    const short* __restrict__ A, const short* __restrict__ Wt,
    const float* __restrict__ bias, void* __restrict__ Cv,
    int M, int N, int K)
{
    __shared__ __align__(16) short As[2][128 * 64];
    __shared__ __align__(16) short Bs[2][64 * 64];

    const int tid = threadIdx.x;
    const int lane = tid & 63;
    const int wave = tid >> 6;
    const int rowBase = blockIdx.x * 128;
    const int colBase = blockIdx.y * 64;

    const int sr = lane >> 3;
    const int sc = ((lane & 7) ^ sr) << 3;

    const short* gA[4];
    #pragma unroll
    for (int c = 0; c < 4; ++c)
        gA[c] = A + (size_t)min(rowBase + wave * 32 + c * 8 + sr, M - 1) * K + sc;
    const short* gB[2];
    #pragma unroll
    for (int c = 0; c < 2; ++c)
        gB[c] = Wt + (size_t)(colBase + wave * 16 + c * 8 + sr) * K + sc;

    const int frow = lane & 15;
    const int g4 = lane >> 4;
    const int r7 = frow & 7;
    const int wm = wave * 32;

    f32x4 acc[2][4] = {};

    auto stage = [&](int buf, int k0) {
        #pragma unroll
        for (int c = 0; c < 4; ++c)
            gll16(gA[c] + k0, &As[buf][(wave * 32 + c * 8) * 64]);
        #pragma unroll
        for (int c = 0; c < 2; ++c)
            gll16(gB[c] + k0, &Bs[buf][(wave * 16 + c * 8) * 64]);
    };

    stage(0, 0);

    int cur = 0;
    for (int k0 = 0; k0 < K; k0 += 64) {
        if (k0 + 64 < K) {
            stage(cur ^ 1, k0 + 64);
            asm volatile("s_waitcnt vmcnt(6)" ::: "memory");
        } else {
            asm volatile("s_waitcnt vmcnt(0)" ::: "memory");
        }
        SBAR();
        #pragma unroll
        for (int kk8 = 0; kk8 < 8; kk8 += 4) {
            const int ua = (((kk8 + g4) ^ r7) << 3);
            bf16x8 af0 = *(const bf16x8*)&As[cur][(wm + frow) * 64 + ua];
            bf16x8 af1 = *(const bf16x8*)&As[cur][(wm + 16 + frow) * 64 + ua];
            #pragma unroll
            for (int j = 0; j < 4; ++j) {
                bf16x8 bfj = *(const bf16x8*)&Bs[cur][(j * 16 + frow) * 64 + ua];
                acc[0][j] = MFMA16(af0, bfj, acc[0][j]);
                acc[1][j] = MFMA16(af1, bfj, acc[1][j]);
            }
        }
        SBAR();
        cur ^= 1;
    }

    const int erow = (lane >> 4) * 4;
    const int ecol = lane & 15;
    #pragma unroll
    for (int mi = 0; mi < 2; ++mi) {
        #pragma unroll
        for (int j = 0; j < 4; ++j) {
            #pragma unroll
            for (int r = 0; r < 4; ++r) {
                int row = rowBase + wm + mi * 16 + erow + r;
                if (row < M) {
                    int col = colBase + j * 16 + ecol;
                    float v = acc[mi][j][r] + bias[col];
                    if (RELU) v = fmaxf(v, 0.f);
                    if (OUTBF) ((short*)Cv)[(size_t)row * N + col] = f2b(v);
                    else       ((float*)Cv)[(size_t)row * N + col] = v;
                }
            }
        }
    }
}

// ---------------------------------------------------------------------------
// GEMM (N=256 fixed) + residual + LayerNorm fused epilogue. BM=16 (grid 481),
// 4 waves each own a 64-col slice. Counted vmcnt + swizzle (r4-verified).
// Writes: out fp32, xb = bf16(out), (WRITEQ) qb = bf16(out + pos).
// ---------------------------------------------------------------------------
template<int WRITEQ>
__global__ __launch_bounds__(256) void gemm_ln_kernel(
    const short* __restrict__ A, const short* __restrict__ Wt,
    const float* __restrict__ bias, const float* __restrict__ g,
    const float* __restrict__ bln, const float* __restrict__ pos,
    float* __restrict__ out, short* __restrict__ xb, short* __restrict__ qb,
    int M, int K)
{
    __shared__ __align__(16) short As[2][16 * 64];
    __shared__ __align__(16) short Bs[2][256 * 64];
    __shared__ float rsum[16][4], rsq[16][4], smu[16], srs[16];

    const int tid = threadIdx.x;
    const int lane = tid & 63;
    const int wave = tid >> 6;
    const int rowBase = blockIdx.x * 16;

    const int sr = lane >> 3;
    const int sc = ((lane & 7) ^ sr) << 3;

    const short* gA = A + (size_t)min(rowBase + wave * 8 + sr, M - 1) * K + sc;
    const short* gB[8];
    #pragma unroll
    for (int c = 0; c < 8; ++c)
        gB[c] = Wt + (size_t)(wave * 64 + c * 8 + sr) * K + sc;

    const int frow = lane & 15;
    const int g4 = lane >> 4;
    const int r7 = frow & 7;

    f32x4 acc[4] = {};

    auto stage = [&](int buf, int k0) {
        if (wave < 2) gll16(gA + k0, &As[buf][(wave * 8) * 64]);
        #pragma unroll
        for (int c = 0; c < 8; ++c)
            gll16(gB[c] + k0, &Bs[buf][(wave * 64 + c * 8) * 64]);
    };

    stage(0, 0);

    int cur = 0;
    for (int k0 = 0; k0 < K; k0 += 64) {
        if (k0 + 64 < K) {
            stage(cur ^ 1, k0 + 64);
            if (wave < 2) asm volatile("s_waitcnt vmcnt(9)" ::: "memory");
            else          asm volatile("s_waitcnt vmcnt(8)" ::: "memory");
        } else {
            asm volatile("s_waitcnt vmcnt(0)" ::: "memory");
        }
        SBAR();
        #pragma unroll
        for (int kk8 = 0; kk8 < 8; kk8 += 4) {
            const int ua = (((kk8 + g4) ^ r7) << 3);
            bf16x8 af = *(const bf16x8*)&As[cur][frow * 64 + ua];
            #pragma unroll
            for (int j = 0; j < 4; ++j) {
                bf16x8 bfj = *(const bf16x8*)&Bs[cur][(wave * 64 + j * 16 + frow) * 64 + ua];
                acc[j] = MFMA16(af, bfj, acc[j]);
            }
        }
        SBAR();
        cur ^= 1;
    }

    const int erow = (lane >> 4) * 4;
    const int ecol = lane & 15;
    float x[4][4];
    #pragma unroll
    for (int j = 0; j < 4; ++j)
        #pragma unroll
        for (int r = 0; r < 4; ++r) {
            int row = rowBase + erow + r;
            int col = wave * 64 + j * 16 + ecol;
            float res = (row < M) ? out[(size_t)row * 256 + col] : 0.f;
            x[j][r] = acc[j][r] + bias[col] + res;
        }

    #pragma unroll
    for (int r = 0; r < 4; ++r) {
        float s1 = x[0][r] + x[1][r] + x[2][r] + x[3][r];
        float s2 = x[0][r]*x[0][r] + x[1][r]*x[1][r]
                 + x[2][r]*x[2][r] + x[3][r]*x[3][r];
        #pragma unroll
        for (int o = 1; o < 16; o <<= 1) {
            s1 += __shfl_xor(s1, o);
            s2 += __shfl_xor(s2, o);
        }
        if ((lane & 15) == 0) {
            rsum[erow + r][wave] = s1;
            rsq [erow + r][wave] = s2;
        }
    }
    __syncthreads();
    if (tid < 16) {
        float S1 = rsum[tid][0] + rsum[tid][1] + rsum[tid][2] + rsum[tid][3];
        float S2 = rsq[tid][0] + rsq[tid][1] + rsq[tid][2] + rsq[tid][3];
        float mu = S1 * (1.f / 256.f);
        smu[tid] = mu;
        srs[tid] = rsqrtf(S2 * (1.f / 256.f) - mu * mu + 1e-5f);
    }
    __syncthreads();

    #pragma unroll
    for (int r = 0; r < 4; ++r) {
        int lrow = erow + r;
        int row = rowBase + lrow;
        if (row >= M) continue;
        float mu = smu[lrow], rs = srs[lrow];
        #pragma unroll
        for (int j = 0; j < 4; ++j) {
            int col = wave * 64 + j * 16 + ecol;
            float y = (x[j][r] - mu) * rs * g[col] + bln[col];
            out[(size_t)row * 256 + col] = y;
            xb[(size_t)row * 256 + col] = f2b(y);
            if (WRITEQ)
                qb[(size_t)row * 256 + col] = f2b(y + pos[(size_t)row * 256 + col]);
        }
    }
}

// ---------------------------------------------------------------------------
// MSDA sampling v5: prep phase and sIdx/sWgt LDS removed — each sampling
// lane (q, head, dim-group) computes its 16 points' indices + bilinear
// weights in registers (ref point hoisted: fixed per lane). LDS 36->12KB,
// 2 fewer barriers; gathers latency-bound -> occupancy gain hides them.
// grid = 968 = 8*121 (XCD-contiguous swizzle).
// ---------------------------------------------------------------------------
__global__ __launch_bounds__(256) void msda_kernel(
    const short* __restrict__ value, const float* __restrict__ offb,
    short* __restrict__ msdab)
{
    __shared__ float soff[8 * 384];   // 12KB

    const int bid = blockIdx.x;
    const int sb = (bid & 7) * 121 + (bid >> 3);
    const int q0 = sb * 8;
    if (q0 >= S_TOTAL) return;
    const int tid = threadIdx.x;

    // stage 8 rows of offb as float4 (96 float4/row)
    {
        const float4* src4 = (const float4*)offb;
        #pragma unroll
        for (int i = tid; i < 768; i += 256) {
            int qi = i / 96, j = i - qi * 96;
            int q = min(q0 + qi, S_TOTAL - 1);
            *(float4*)&soff[qi * 384 + j * 4] = src4[(size_t)q * 96 + j];
        }
    }
    __syncthreads();

    // softmax per (query, head): 64 pairs
    if (tid < 64) {
        const int qi = tid >> 3, m = tid & 7;
        float* lg = &soff[qi * 384 + 256 + m * 16];
        float mx = -1e30f;
        #pragma unroll
        for (int k = 0; k < 16; ++k) mx = fmaxf(mx, lg[k]);
        float e[16], sum = 0.f;
        #pragma unroll
        for (int k = 0; k < 16; ++k) { e[k] = expf(lg[k] - mx); sum += e[k]; }
        float inv = 1.f / sum;
        #pragma unroll
        for (int k = 0; k < 16; ++k) lg[k] = e[k] * inv;
    }
    __syncthreads();

    const int lane = tid & 63;
    const int qi = (tid >> 6) * 2 + (lane >> 5);
    const int q = q0 + qi;
    if (q >= S_TOTAL) return;
    const int l32 = lane & 31;
    const int h = l32 >> 2, dg = l32 & 3;
    const short* vcol = value + h * 32 + dg * 8;

    // reference point: fixed per lane (computed once, not per item)
    float refx, refy;
    if (q < 5776)      { int t = q;        int r = t / 76, c = t % 76; refx = (c + 0.5f) / 76.f; refy = (r + 0.5f) / 76.f; }
    else if (q < 7220) { int t = q - 5776; int r = t / 38, c = t % 38; refx = (c + 0.5f) / 38.f; refy = (r + 0.5f) / 38.f; }
    else if (q < 7581) { int t = q - 7220; int r = t / 19, c = t % 19; refx = (c + 0.5f) / 19.f; refy = (r + 0.5f) / 19.f; }
    else               { int t = q - 7581; int r = t / 10, c = t % 10; refx = (c + 0.5f) / 10.f; refy = (r + 0.5f) / 10.f; }

    const float* so = &soff[qi * 384];
    float a[8] = {};
    #pragma unroll
    for (int pt = 0; pt < 16; ++pt) {
        const int LVL_HW[4] = {76, 38, 19, 10};
        const int LVL_ST[4] = {0, 5776, 7220, 7581};
        const int lvl = pt >> 2;           // unroll-static
        const int W = LVL_HW[lvl];
        const int base = LVL_ST[lvl];
        const float fW = (float)W;
        const int i = h * 16 + pt;

        float ox = so[i * 2];
        float oy = so[i * 2 + 1];
        float aw = so[256 + i];

        float x = refx * fW + ox - 0.5f;
        float y = refy * fW + oy - 0.5f;
        float x0f = floorf(x), y0f = floorf(y);
        int x0 = (int)x0f, y0 = (int)y0f;
        float dx = x - x0f, dy = y - y0f;

        bool vx0 = (x0 >= 0) & (x0 < W);
        bool vx1 = (x0 >= -1) & (x0 < W - 1);
        bool vy0 = (y0 >= 0) & (y0 < W);
        bool vy1 = (y0 >= -1) & (y0 < W - 1);
        int xc0 = min(max(x0, 0), W - 1), xc1 = min(max(x0 + 1, 0), W - 1);
        int yc0 = min(max(y0, 0), W - 1), yc1 = min(max(y0 + 1, 0), W - 1);
        int i00 = base + yc0 * W + xc0;
        int i01 = base + yc0 * W + xc1;
        int i10 = base + yc1 * W + xc0;
        int i11 = base + yc1 * W + xc1;
        float w00 = (vy0 && vx0) ? (1.f - dy) * (1.f - dx) * aw : 0.f;
        float w01 = (vy0 && vx1) ? (1.f - dy) * dx * aw : 0.f;
        float w10 = (vy1 && vx0) ? dy * (1.f - dx) * aw : 0.f;
        float w11 = (vy1 && vx1) ? dy * dx * aw : 0.f;

        bf16x8 v0 = *(const bf16x8*)(vcol + ((size_t)i00 << 8));
        bf16x8 v1 = *(const bf16x8*)(vcol + ((size_t)i01 << 8));
        bf16x8 v2 = *(const bf16x8*)(vcol + ((size_t)i10 << 8));
        bf16x8 v3 = *(const bf16x8*)(vcol + ((size_t)i11 << 8));
        #pragma unroll
        for (int e = 0; e < 8; ++e)
            a[e] += w00 * b2f((unsigned short)v0[e]) + w01 * b2f((unsigned short)v1[e])
                  + w10 * b2f((unsigned short)v2[e]) + w11 * b2f((unsigned short)v3[e]);
    }
    bf16x8 o;
    #pragma unroll
    for (int e = 0; e < 8; ++e) o[e] = f2b(a[e]);
    *(bf16x8*)(msdab + (size_t)q * 256 + h * 32 + dg * 8) = o;
}

// ---------------------------------------------------------------------------
extern "C" void kernel_launch(void* const* d_in, const int* in_sizes, int n_in,
                              void* d_out, int out_size, void* d_ws, size_t ws_size,
                              hipStream_t stream) {
    const float* src    = (const float*)d_in[0];
    const float* pos    = (const float*)d_in[1];
    const float* W_off  = (const float*)d_in[6];
    const float* b_off  = (const float*)d_in[7];
    const float* W_attn = (const float*)d_in[8];
    const float* b_attn = (const float*)d_in[9];
    const float* W_val  = (const float*)d_in[10];
    const float* b_val  = (const float*)d_in[11];
    const float* W_out  = (const float*)d_in[12];
    const float* b_out  = (const float*)d_in[13];
    const float* ln1_g  = (const float*)d_in[14];
    const float* ln1_b  = (const float*)d_in[15];
    const float* W_ff1  = (const float*)d_in[16];
    const float* b_ff1  = (const float*)d_in[17];
    const float* W_ff2  = (const float*)d_in[18];
    const float* b_ff2  = (const float*)d_in[19];
    const float* ln2_g  = (const float*)d_in[20];
    const float* ln2_b  = (const float*)d_in[21];

    const size_t S = S_TOTAL;
    float* out = (float*)d_out;

    // --- workspace layout ---
    short* wt = (short*)d_ws;
    short* Wt_val = wt;             // 3 x [256][256]
    short* Wt_oa  = wt + 196608;    // 3 x [384][256]
    short* Wt_out = wt + 491520;    // 3 x [256][256]
    short* Wt_ff1 = wt + 688128;    // 3 x [1024][256]
    short* Wt_ff2 = wt + 1474560;   // 3 x [256][1024]
    float* fbase  = (float*)d_ws + 1131648;
    short* xb       = (short*)fbase;               // [S][256] bf16
    short* qb       = (short*)(fbase + 128 * S);   // [S][256] bf16
    short* value_bf = (short*)(fbase + 256 * S);   // [S][256] bf16
    float* offb     = fbase + 384 * S;             // [S][384] fp32
    short* msdab    = (short*)(fbase + 768 * S);   // [S][256] bf16
    short* hid      = (short*)(fbase + 256 * S);   // [S][1024] bf16 (FFN phase; overlaps value+offb)

    transpose_cvt_kernel<<<dim3(1377, 1, 3), 256, 0, stream>>>(
        W_val, W_off, W_attn, W_out, W_ff1, W_ff2,
        Wt_val, Wt_oa, Wt_oa + 65536, Wt_out, Wt_ff1, Wt_ff2,
        (const float4*)src, (const float4*)pos,
        (float4*)out, (ushort4*)xb, (ushort4*)qb);

    const int MB = (S_TOTAL + 127) / 128;     // 61
    const int LB = (S_TOTAL + 15) / 16;       // 481

    for (int l = 0; l < 3; ++l) {
        // value (bf16) + off/attn (fp32) in one dispatch
        gemm_va_kernel<<<dim3(MB, 10), 256, 0, stream>>>(
            xb, qb, Wt_val + (size_t)l * 65536, Wt_oa + (size_t)l * 98304,
            b_val + (size_t)l * 256, b_off + (size_t)l * 256, b_attn + (size_t)l * 128,
            value_bf, offb, S_TOTAL);
        // sampling -> bf16
        msda_kernel<<<968, 256, 0, stream>>>(value_bf, offb, msdab);
        // out = LN1(out + msdab @ Wout + bout); xb = bf16(out)
        gemm_ln_kernel<0><<<LB, 256, 0, stream>>>(
            msdab, Wt_out + (size_t)l * 65536, b_out + (size_t)l * 256,
            ln1_g + (size_t)l * 256, ln1_b + (size_t)l * 256, pos,
            out, xb, qb, S_TOTAL, 256);
        // hid = bf16(relu(xb @ Wff1 + b))
        gemm_kernel<1, 1><<<dim3(MB, 16), 256, 0, stream>>>(
            xb, Wt_ff1 + (size_t)l * 262144, b_ff1 + (size_t)l * 1024, hid,
            S_TOTAL, 1024, 256);
        // out = LN2(out + hid @ Wff2 + b); xb, qb for next layer
        gemm_ln_kernel<1><<<LB, 256, 0, stream>>>(
            hid, Wt_ff2 + (size_t)l * 262144, b_ff2 + (size_t)l * 256,
            ln2_g + (size_t)l * 256, ln2_b + (size_t)l * 256, pos,
            out, xb, qb, S_TOTAL, 1024);
    }
}

// Round 9
// 367.426 us; speedup vs baseline: 1.1640x; 1.0567x over previous
//
#include <hip/hip_runtime.h>
#include <hip/hip_bf16.h>
#include <math.h>

#define S_TOTAL 7681

typedef __attribute__((ext_vector_type(8))) short bf16x8;
typedef __attribute__((ext_vector_type(4))) float f32x4;

// fp32 -> bf16 round-to-nearest-even
__device__ __forceinline__ short f2b(float x) {
    union { float f; unsigned u; } v; v.f = x;
    unsigned r = v.u + 0x7FFFu + ((v.u >> 16) & 1u);
    return (short)(r >> 16);
}
__device__ __forceinline__ float b2f(unsigned short u) {
    union { unsigned u; float f; } t; t.u = ((unsigned)u) << 16; return t.f;
}

// async global->LDS, 16B/lane. LDS dest: wave-uniform base + lane*16 (linear).
__device__ __forceinline__ void gll16(const short* g, short* l) {
    __builtin_amdgcn_global_load_lds(
        (const __attribute__((address_space(1))) unsigned int*)g,
        (__attribute__((address_space(3))) unsigned int*)l,
        16, 0, 0);
}

// raw barrier: no compiler-inserted vmcnt(0) drain (unlike __syncthreads)
#define SBAR() asm volatile("s_barrier" ::: "memory")

#define MFMA16(a, b, c) __builtin_amdgcn_mfma_f32_16x16x32_bf16(a, b, c, 0, 0, 0)

// ---------------------------------------------------------------------------
// Weight transpose + convert (W[K][N] fp32 -> Wt[N][K] bf16), PLUS the
// src/pos cvt_copy folded into the same dispatch (blocks t >= 736).
// grid = (736 + 641, 1, 3)
// ---------------------------------------------------------------------------
__global__ __launch_bounds__(256) void transpose_cvt_kernel(
    const float* __restrict__ s0, const float* __restrict__ s1,
    const float* __restrict__ s2, const float* __restrict__ s3,
    const float* __restrict__ s4, const float* __restrict__ s5,
    short* __restrict__ d0, short* __restrict__ d1, short* __restrict__ d2,
    short* __restrict__ d3, short* __restrict__ d4, short* __restrict__ d5,
    const float4* __restrict__ csrc, const float4* __restrict__ cpos,
    float4* __restrict__ co, ushort4* __restrict__ cxb, ushort4* __restrict__ cqb)
{
    const int z = blockIdx.z;
    int t = blockIdx.x;
    if (t >= 736) {
        // cvt_copy part: out = src; xb = bf16(src); qb = bf16(src + pos)
        const int n4 = S_TOTAL * 64;
        int i = (z * 641 + (t - 736)) * 256 + threadIdx.x;
        if (i < n4) {
            float4 v = csrc[i], p = cpos[i];
            co[i] = v;
            ushort4 h, hq;
            h.x = (unsigned short)f2b(v.x); h.y = (unsigned short)f2b(v.y);
            h.z = (unsigned short)f2b(v.z); h.w = (unsigned short)f2b(v.w);
            hq.x = (unsigned short)f2b(v.x + p.x); hq.y = (unsigned short)f2b(v.y + p.y);
            hq.z = (unsigned short)f2b(v.z + p.z); hq.w = (unsigned short)f2b(v.w + p.w);
            cxb[i] = h;
            cqb[i] = hq;
        }
        return;
    }
    const float* src; short* dst; int K, N, lt;
    if (t < 64)       { src = s0 + (size_t)z * 65536;  dst = d0 + (size_t)z * 65536;  K = 256;  N = 256;  lt = t; }
    else if (t < 128) { src = s1 + (size_t)z * 65536;  dst = d1 + (size_t)z * 98304;  K = 256;  N = 256;  lt = t - 64; }
    else if (t < 160) { src = s2 + (size_t)z * 32768;  dst = d2 + (size_t)z * 98304;  K = 256;  N = 128;  lt = t - 128; }
    else if (t < 224) { src = s3 + (size_t)z * 65536;  dst = d3 + (size_t)z * 65536;  K = 256;  N = 256;  lt = t - 160; }
    else if (t < 480) { src = s4 + (size_t)z * 262144; dst = d4 + (size_t)z * 262144; K = 256;  N = 1024; lt = t - 224; }
    else              { src = s5 + (size_t)z * 262144; dst = d5 + (size_t)z * 262144; K = 1024; N = 256;  lt = t - 480; }
    const int ntx = N >> 5;
    const int tk = (lt / ntx) << 5, tn = (lt % ntx) << 5;
    __shared__ float tile[32][33];
    const int cx = threadIdx.x & 31, cy = threadIdx.x >> 5;
    #pragma unroll
    for (int i = 0; i < 32; i += 8)
        tile[cy + i][cx] = src[(size_t)(tk + cy + i) * N + tn + cx];
    __syncthreads();
    #pragma unroll
    for (int i = 0; i < 32; i += 8)
        dst[(size_t)(tn + cy + i) * K + tk + cx] = f2b(tile[cx][cy + i]);
}

// ---------------------------------------------------------------------------
// Merged value + off/attn GEMM (K=256), 128x64 tile, BK=64, gll staging,
// counted vmcnt, both-sides XOR swizzle (r4-verified). grid (61, 10).
// ---------------------------------------------------------------------------
__global__ __launch_bounds__(256) void gemm_va_kernel(
    const short* __restrict__ xb, const short* __restrict__ qb,
    const short* __restrict__ Wt_val, const short* __restrict__ Wt_oa,
    const float* __restrict__ b_val, const float* __restrict__ b_off,
    const float* __restrict__ b_attn,
    short* __restrict__ value_bf, float* __restrict__ offbuf, int M)
{
    const int grp = (blockIdx.y >= 4);
    const short* A  = grp ? qb : xb;
    const short* Wt = grp ? Wt_oa : Wt_val;
    const int colBase = (grp ? (blockIdx.y - 4) : blockIdx.y) * 64;
    const int K = 256;

    __shared__ __align__(16) short As[2][128 * 64];
    __shared__ __align__(16) short Bs[2][64 * 64];

    const int tid = threadIdx.x;
    const int lane = tid & 63;
    const int wave = tid >> 6;
    const int rowBase = blockIdx.x * 128;

    const int sr = lane >> 3;
    const int sc = ((lane & 7) ^ sr) << 3;

    const short* gA[4];
    #pragma unroll
    for (int c = 0; c < 4; ++c)
        gA[c] = A + (size_t)min(rowBase + wave * 32 + c * 8 + sr, M - 1) * K + sc;
    const short* gB[2];
    #pragma unroll
    for (int c = 0; c < 2; ++c)
        gB[c] = Wt + (size_t)(colBase + wave * 16 + c * 8 + sr) * K + sc;

    const int frow = lane & 15;
    const int g4 = lane >> 4;
    const int r7 = frow & 7;
    const int wm = wave * 32;

    f32x4 acc[2][4] = {};

    auto stage = [&](int buf, int k0) {
        #pragma unroll
        for (int c = 0; c < 4; ++c)
            gll16(gA[c] + k0, &As[buf][(wave * 32 + c * 8) * 64]);
        #pragma unroll
        for (int c = 0; c < 2; ++c)
            gll16(gB[c] + k0, &Bs[buf][(wave * 16 + c * 8) * 64]);
    };

    stage(0, 0);

    int cur = 0;
    for (int k0 = 0; k0 < K; k0 += 64) {
        if (k0 + 64 < K) {
            stage(cur ^ 1, k0 + 64);
            asm volatile("s_waitcnt vmcnt(6)" ::: "memory");
        } else {
            asm volatile("s_waitcnt vmcnt(0)" ::: "memory");
        }
        SBAR();
        #pragma unroll
        for (int kk8 = 0; kk8 < 8; kk8 += 4) {
            const int ua = (((kk8 + g4) ^ r7) << 3);
            bf16x8 af0 = *(const bf16x8*)&As[cur][(wm + frow) * 64 + ua];
            bf16x8 af1 = *(const bf16x8*)&As[cur][(wm + 16 + frow) * 64 + ua];
            #pragma unroll
            for (int j = 0; j < 4; ++j) {
                bf16x8 bfj = *(const bf16x8*)&Bs[cur][(j * 16 + frow) * 64 + ua];
                acc[0][j] = MFMA16(af0, bfj, acc[0][j]);
                acc[1][j] = MFMA16(af1, bfj, acc[1][j]);
            }
        }
        SBAR();
        cur ^= 1;
    }

    const int erow = (lane >> 4) * 4;
    const int ecol = lane & 15;
    #pragma unroll
    for (int mi = 0; mi < 2; ++mi) {
        #pragma unroll
        for (int j = 0; j < 4; ++j) {
            int col = colBase + j * 16 + ecol;
            float bias = grp ? (col < 256 ? b_off[col] : b_attn[col - 256]) : b_val[col];
            #pragma unroll
            for (int r = 0; r < 4; ++r) {
                int row = rowBase + wm + mi * 16 + erow + r;
                if (row < M) {
                    float v = acc[mi][j][r] + bias;
                    if (grp) offbuf[(size_t)row * 384 + col] = v;
                    else     value_bf[(size_t)row * 256 + col] = f2b(v);
                }
            }
        }
    }
}

// ---------------------------------------------------------------------------
// Plain GEMM + bias (+relu). Used for ff1 (M=7681, N=1024, K=256).
// r4-verified.
// ---------------------------------------------------------------------------
template<int RELU, int OUTBF>
__global__ __launch_bounds__(256) void gemm_kernel(
    const short* __restrict__ A, const short* __restrict__ Wt,
    const float* __restrict__ bias, void* __restrict__ Cv,
    int M, int N, int K)
{
    __shared__ __align__(16) short As[2][128 * 64];
    __shared__ __align__(16) short Bs[2][64 * 64];

    const int tid = threadIdx.x;
    const int lane = tid & 63;
    const int wave = tid >> 6;
    const int rowBase = blockIdx.x * 128;
    const int colBase = blockIdx.y * 64;

    const int sr = lane >> 3;
    const int sc = ((lane & 7) ^ sr) << 3;

    const short* gA[4];
    #pragma unroll
    for (int c = 0; c < 4; ++c)
        gA[c] = A + (size_t)min(rowBase + wave * 32 + c * 8 + sr, M - 1) * K + sc;
    const short* gB[2];
    #pragma unroll
    for (int c = 0; c < 2; ++c)
        gB[c] = Wt + (size_t)(colBase + wave * 16 + c * 8 + sr) * K + sc;

    const int frow = lane & 15;
    const int g4 = lane >> 4;
    const int r7 = frow & 7;
    const int wm = wave * 32;

    f32x4 acc[2][4] = {};

    auto stage = [&](int buf, int k0) {
        #pragma unroll
        for (int c = 0; c < 4; ++c)
            gll16(gA[c] + k0, &As[buf][(wave * 32 + c * 8) * 64]);
        #pragma unroll
        for (int c = 0; c < 2; ++c)
            gll16(gB[c] + k0, &Bs[buf][(wave * 16 + c * 8) * 64]);
    };

    stage(0, 0);

    int cur = 0;
    for (int k0 = 0; k0 < K; k0 += 64) {
        if (k0 + 64 < K) {
            stage(cur ^ 1, k0 + 64);
            asm volatile("s_waitcnt vmcnt(6)" ::: "memory");
        } else {
            asm volatile("s_waitcnt vmcnt(0)" ::: "memory");
        }
        SBAR();
        #pragma unroll
        for (int kk8 = 0; kk8 < 8; kk8 += 4) {
            const int ua = (((kk8 + g4) ^ r7) << 3);
            bf16x8 af0 = *(const bf16x8*)&As[cur][(wm + frow) * 64 + ua];
            bf16x8 af1 = *(const bf16x8*)&As[cur][(wm + 16 + frow) * 64 + ua];
            #pragma unroll
            for (int j = 0; j < 4; ++j) {
                bf16x8 bfj = *(const bf16x8*)&Bs[cur][(j * 16 + frow) * 64 + ua];
                acc[0][j] = MFMA16(af0, bfj, acc[0][j]);
                acc[1][j] = MFMA16(af1, bfj, acc[1][j]);
            }
        }
        SBAR();
        cur ^= 1;
    }

    const int erow = (lane >> 4) * 4;
    const int ecol = lane & 15;
    #pragma unroll
    for (int mi = 0; mi < 2; ++mi) {
        #pragma unroll
        for (int j = 0; j < 4; ++j) {
            #pragma unroll
            for (int r = 0; r < 4; ++r) {
                int row = rowBase + wm + mi * 16 + erow + r;
                if (row < M) {
                    int col = colBase + j * 16 + ecol;
                    float v = acc[mi][j][r] + bias[col];
                    if (RELU) v = fmaxf(v, 0.f);
                    if (OUTBF) ((short*)Cv)[(size_t)row * N + col] = f2b(v);
                    else       ((float*)Cv)[(size_t)row * N + col] = v;
                }
            }
        }
    }
}

// ---------------------------------------------------------------------------
// GEMM (N=256 fixed) + residual + LayerNorm fused epilogue. BM=16 (grid 481),
// 4 waves each own a 64-col slice. Counted vmcnt + swizzle (r4-verified).
// Writes: out fp32, xb = bf16(out), (WRITEQ) qb = bf16(out + pos).
// ---------------------------------------------------------------------------
template<int WRITEQ>
__global__ __launch_bounds__(256) void gemm_ln_kernel(
    const short* __restrict__ A, const short* __restrict__ Wt,
    const float* __restrict__ bias, const float* __restrict__ g,
    const float* __restrict__ bln, const float* __restrict__ pos,
    float* __restrict__ out, short* __restrict__ xb, short* __restrict__ qb,
    int M, int K)
{
    __shared__ __align__(16) short As[2][16 * 64];
    __shared__ __align__(16) short Bs[2][256 * 64];
    __shared__ float rsum[16][4], rsq[16][4], smu[16], srs[16];

    const int tid = threadIdx.x;
    const int lane = tid & 63;
    const int wave = tid >> 6;
    const int rowBase = blockIdx.x * 16;

    const int sr = lane >> 3;
    const int sc = ((lane & 7) ^ sr) << 3;

    const short* gA = A + (size_t)min(rowBase + wave * 8 + sr, M - 1) * K + sc;
    const short* gB[8];
    #pragma unroll
    for (int c = 0; c < 8; ++c)
        gB[c] = Wt + (size_t)(wave * 64 + c * 8 + sr) * K + sc;

    const int frow = lane & 15;
    const int g4 = lane >> 4;
    const int r7 = frow & 7;

    f32x4 acc[4] = {};

    auto stage = [&](int buf, int k0) {
        if (wave < 2) gll16(gA + k0, &As[buf][(wave * 8) * 64]);
        #pragma unroll
        for (int c = 0; c < 8; ++c)
            gll16(gB[c] + k0, &Bs[buf][(wave * 64 + c * 8) * 64]);
    };

    stage(0, 0);

    int cur = 0;
    for (int k0 = 0; k0 < K; k0 += 64) {
        if (k0 + 64 < K) {
            stage(cur ^ 1, k0 + 64);
            if (wave < 2) asm volatile("s_waitcnt vmcnt(9)" ::: "memory");
            else          asm volatile("s_waitcnt vmcnt(8)" ::: "memory");
        } else {
            asm volatile("s_waitcnt vmcnt(0)" ::: "memory");
        }
        SBAR();
        #pragma unroll
        for (int kk8 = 0; kk8 < 8; kk8 += 4) {
            const int ua = (((kk8 + g4) ^ r7) << 3);
            bf16x8 af = *(const bf16x8*)&As[cur][frow * 64 + ua];
            #pragma unroll
            for (int j = 0; j < 4; ++j) {
                bf16x8 bfj = *(const bf16x8*)&Bs[cur][(wave * 64 + j * 16 + frow) * 64 + ua];
                acc[j] = MFMA16(af, bfj, acc[j]);
            }
        }
        SBAR();
        cur ^= 1;
    }

    const int erow = (lane >> 4) * 4;
    const int ecol = lane & 15;
    float x[4][4];
    #pragma unroll
    for (int j = 0; j < 4; ++j)
        #pragma unroll
        for (int r = 0; r < 4; ++r) {
            int row = rowBase + erow + r;
            int col = wave * 64 + j * 16 + ecol;
            float res = (row < M) ? out[(size_t)row * 256 + col] : 0.f;
            x[j][r] = acc[j][r] + bias[col] + res;
        }

    #pragma unroll
    for (int r = 0; r < 4; ++r) {
        float s1 = x[0][r] + x[1][r] + x[2][r] + x[3][r];
        float s2 = x[0][r]*x[0][r] + x[1][r]*x[1][r]
                 + x[2][r]*x[2][r] + x[3][r]*x[3][r];
        #pragma unroll
        for (int o = 1; o < 16; o <<= 1) {
            s1 += __shfl_xor(s1, o);
            s2 += __shfl_xor(s2, o);
        }
        if ((lane & 15) == 0) {
            rsum[erow + r][wave] = s1;
            rsq [erow + r][wave] = s2;
        }
    }
    __syncthreads();
    if (tid < 16) {
        float S1 = rsum[tid][0] + rsum[tid][1] + rsum[tid][2] + rsum[tid][3];
        float S2 = rsq[tid][0] + rsq[tid][1] + rsq[tid][2] + rsq[tid][3];
        float mu = S1 * (1.f / 256.f);
        smu[tid] = mu;
        srs[tid] = rsqrtf(S2 * (1.f / 256.f) - mu * mu + 1e-5f);
    }
    __syncthreads();

    #pragma unroll
    for (int r = 0; r < 4; ++r) {
        int lrow = erow + r;
        int row = rowBase + lrow;
        if (row >= M) continue;
        float mu = smu[lrow], rs = srs[lrow];
        #pragma unroll
        for (int j = 0; j < 4; ++j) {
            int col = wave * 64 + j * 16 + ecol;
            float y = (x[j][r] - mu) * rs * g[col] + bln[col];
            out[(size_t)row * 256 + col] = y;
            xb[(size_t)row * 256 + col] = f2b(y);
            if (WRITEQ)
                qb[(size_t)row * 256 + col] = f2b(y + pos[(size_t)row * 256 + col]);
        }
    }
}

// ---------------------------------------------------------------------------
// MSDA sampling v6: 1 query per WAVE (64 lanes = 8 heads x 8 dim-groups of
// 4 dims), 4 queries/block. Per-wave staging + wave-parallel softmax ->
// zero block barriers; all LDS deps are in-wave (compiler-tracked).
// soff padded layout (off: h*33 + pt*2; attn: 264 + h*17 + pt) -> the 8
// active heads hit 8 distinct banks (33h=h, 17h distinct mod 32).
// Doubles wave count vs v5 (7.5 waves/SIMD of work) and halves per-lane
// VALU -> hides the random L2 gather latency. grid = 1921 (bijective
// XCD swizzle). LDS 6.4KB.
// ---------------------------------------------------------------------------
__global__ __launch_bounds__(256) void msda_kernel(
    const short* __restrict__ value, const float* __restrict__ offb,
    short* __restrict__ msdab)
{
    __shared__ float soff[4 * 400];   // 6.4KB, padded per-head

    const int bid = blockIdx.x;
    const int sb = (bid < 1920) ? ((bid & 7) * 240 + (bid >> 3)) : bid;
    const int q0 = sb * 4;
    const int tid = threadIdx.x;
    const int lane = tid & 63;
    const int wave = tid >> 6;

    const int q = q0 + wave;
    const int qc = min(q, S_TOTAL - 1);
    float* row = &soff[wave * 400];

    // ---- per-wave staging: 96 float4 of offb row -> padded soff layout ----
    {
        const float4* src4 = (const float4*)offb + (size_t)qc * 96;
        #pragma unroll
        for (int i = lane; i < 96; i += 64) {
            float4 v = src4[i];
            int s = i * 4;
            float vv[4] = {v.x, v.y, v.z, v.w};
            #pragma unroll
            for (int k = 0; k < 4; ++k) {
                int sk = s + k;
                int dst;
                if (sk < 256) { int m = sk >> 5, r = sk & 31; dst = m * 33 + r; }
                else          { int j = sk - 256; int m = j >> 4, r = j & 15; dst = 264 + m * 17 + r; }
                row[dst] = vv[k];
            }
        }
    }
    // in-wave dependency: compiler inserts lgkmcnt before the reads below.

    // ---- wave-parallel softmax: m = lane>>3, each lane handles 2 logits ----
    {
        const int m = lane >> 3, j = lane & 7;
        float* lg = row + 264 + m * 17;
        float e0 = lg[j], e1 = lg[j + 8];
        float mx = fmaxf(e0, e1);
        #pragma unroll
        for (int o = 1; o < 8; o <<= 1) mx = fmaxf(mx, __shfl_xor(mx, o));
        e0 = expf(e0 - mx); e1 = expf(e1 - mx);
        float sum = e0 + e1;
        #pragma unroll
        for (int o = 1; o < 8; o <<= 1) sum += __shfl_xor(sum, o);
        float inv = 1.f / sum;
        lg[j] = e0 * inv;
        lg[j + 8] = e1 * inv;
    }

    if (q >= S_TOTAL) return;

    // ---- sampling: h = lane>>3 (head), dg = lane&7 (4 dims = 8B) ----
    const int h = lane >> 3, dg = lane & 7;
    const short* vcol = value + h * 32 + dg * 4;

    // reference point: fixed per lane
    float refx, refy;
    if (q < 5776)      { int t = q;        int r = t / 76, c = t % 76; refx = (c + 0.5f) / 76.f; refy = (r + 0.5f) / 76.f; }
    else if (q < 7220) { int t = q - 5776; int r = t / 38, c = t % 38; refx = (c + 0.5f) / 38.f; refy = (r + 0.5f) / 38.f; }
    else if (q < 7581) { int t = q - 7220; int r = t / 19, c = t % 19; refx = (c + 0.5f) / 19.f; refy = (r + 0.5f) / 19.f; }
    else               { int t = q - 7581; int r = t / 10, c = t % 10; refx = (c + 0.5f) / 10.f; refy = (r + 0.5f) / 10.f; }

    float a[4] = {};
    #pragma unroll
    for (int pt = 0; pt < 16; ++pt) {
        const int LVL_HW[4] = {76, 38, 19, 10};
        const int LVL_ST[4] = {0, 5776, 7220, 7581};
        const int lvl = pt >> 2;           // unroll-static
        const int W = LVL_HW[lvl];
        const int base = LVL_ST[lvl];
        const float fW = (float)W;

        float ox = row[h * 33 + pt * 2];
        float oy = row[h * 33 + pt * 2 + 1];
        float aw = row[264 + h * 17 + pt];

        float x = refx * fW + ox - 0.5f;
        float y = refy * fW + oy - 0.5f;
        float x0f = floorf(x), y0f = floorf(y);
        int x0 = (int)x0f, y0 = (int)y0f;
        float dx = x - x0f, dy = y - y0f;

        bool vx0 = (x0 >= 0) & (x0 < W);
        bool vx1 = (x0 >= -1) & (x0 < W - 1);
        bool vy0 = (y0 >= 0) & (y0 < W);
        bool vy1 = (y0 >= -1) & (y0 < W - 1);
        int xc0 = min(max(x0, 0), W - 1), xc1 = min(max(x0 + 1, 0), W - 1);
        int yc0 = min(max(y0, 0), W - 1), yc1 = min(max(y0 + 1, 0), W - 1);
        int i00 = base + yc0 * W + xc0;
        int i01 = base + yc0 * W + xc1;
        int i10 = base + yc1 * W + xc0;
        int i11 = base + yc1 * W + xc1;
        float w00 = (vy0 && vx0) ? (1.f - dy) * (1.f - dx) * aw : 0.f;
        float w01 = (vy0 && vx1) ? (1.f - dy) * dx * aw : 0.f;
        float w10 = (vy1 && vx0) ? dy * (1.f - dx) * aw : 0.f;
        float w11 = (vy1 && vx1) ? dy * dx * aw : 0.f;

        ushort4 v0 = *(const ushort4*)(vcol + ((size_t)i00 << 8));
        ushort4 v1 = *(const ushort4*)(vcol + ((size_t)i01 << 8));
        ushort4 v2 = *(const ushort4*)(vcol + ((size_t)i10 << 8));
        ushort4 v3 = *(const ushort4*)(vcol + ((size_t)i11 << 8));
        const unsigned short* p0 = (const unsigned short*)&v0;
        const unsigned short* p1 = (const unsigned short*)&v1;
        const unsigned short* p2 = (const unsigned short*)&v2;
        const unsigned short* p3 = (const unsigned short*)&v3;
        #pragma unroll
        for (int e = 0; e < 4; ++e)
            a[e] += w00 * b2f(p0[e]) + w01 * b2f(p1[e])
                  + w10 * b2f(p2[e]) + w11 * b2f(p3[e]);
    }
    short4 o;
    o.x = f2b(a[0]); o.y = f2b(a[1]); o.z = f2b(a[2]); o.w = f2b(a[3]);
    *(short4*)(msdab + (size_t)q * 256 + h * 32 + dg * 4) = o;
}

// ---------------------------------------------------------------------------
extern "C" void kernel_launch(void* const* d_in, const int* in_sizes, int n_in,
                              void* d_out, int out_size, void* d_ws, size_t ws_size,
                              hipStream_t stream) {
    const float* src    = (const float*)d_in[0];
    const float* pos    = (const float*)d_in[1];
    const float* W_off  = (const float*)d_in[6];
    const float* b_off  = (const float*)d_in[7];
    const float* W_attn = (const float*)d_in[8];
    const float* b_attn = (const float*)d_in[9];
    const float* W_val  = (const float*)d_in[10];
    const float* b_val  = (const float*)d_in[11];
    const float* W_out  = (const float*)d_in[12];
    const float* b_out  = (const float*)d_in[13];
    const float* ln1_g  = (const float*)d_in[14];
    const float* ln1_b  = (const float*)d_in[15];
    const float* W_ff1  = (const float*)d_in[16];
    const float* b_ff1  = (const float*)d_in[17];
    const float* W_ff2  = (const float*)d_in[18];
    const float* b_ff2  = (const float*)d_in[19];
    const float* ln2_g  = (const float*)d_in[20];
    const float* ln2_b  = (const float*)d_in[21];

    const size_t S = S_TOTAL;
    float* out = (float*)d_out;

    // --- workspace layout ---
    short* wt = (short*)d_ws;
    short* Wt_val = wt;             // 3 x [256][256]
    short* Wt_oa  = wt + 196608;    // 3 x [384][256]
    short* Wt_out = wt + 491520;    // 3 x [256][256]
    short* Wt_ff1 = wt + 688128;    // 3 x [1024][256]
    short* Wt_ff2 = wt + 1474560;   // 3 x [256][1024]
    float* fbase  = (float*)d_ws + 1131648;
    short* xb       = (short*)fbase;               // [S][256] bf16
    short* qb       = (short*)(fbase + 128 * S);   // [S][256] bf16
    short* value_bf = (short*)(fbase + 256 * S);   // [S][256] bf16
    float* offb     = fbase + 384 * S;             // [S][384] fp32
    short* msdab    = (short*)(fbase + 768 * S);   // [S][256] bf16
    short* hid      = (short*)(fbase + 256 * S);   // [S][1024] bf16 (FFN phase; overlaps value+offb)

    transpose_cvt_kernel<<<dim3(1377, 1, 3), 256, 0, stream>>>(
        W_val, W_off, W_attn, W_out, W_ff1, W_ff2,
        Wt_val, Wt_oa, Wt_oa + 65536, Wt_out, Wt_ff1, Wt_ff2,
        (const float4*)src, (const float4*)pos,
        (float4*)out, (ushort4*)xb, (ushort4*)qb);

    const int MB = (S_TOTAL + 127) / 128;     // 61
    const int LB = (S_TOTAL + 15) / 16;       // 481
    const int SB = (S_TOTAL + 3) / 4;         // 1921

    for (int l = 0; l < 3; ++l) {
        // value (bf16) + off/attn (fp32) in one dispatch
        gemm_va_kernel<<<dim3(MB, 10), 256, 0, stream>>>(
            xb, qb, Wt_val + (size_t)l * 65536, Wt_oa + (size_t)l * 98304,
            b_val + (size_t)l * 256, b_off + (size_t)l * 256, b_attn + (size_t)l * 128,
            value_bf, offb, S_TOTAL);
        // sampling -> bf16
        msda_kernel<<<SB, 256, 0, stream>>>(value_bf, offb, msdab);
        // out = LN1(out + msdab @ Wout + bout); xb = bf16(out)
        gemm_ln_kernel<0><<<LB, 256, 0, stream>>>(
            msdab, Wt_out + (size_t)l * 65536, b_out + (size_t)l * 256,
            ln1_g + (size_t)l * 256, ln1_b + (size_t)l * 256, pos,
            out, xb, qb, S_TOTAL, 256);
        // hid = bf16(relu(xb @ Wff1 + b))
        gemm_kernel<1, 1><<<dim3(MB, 16), 256, 0, stream>>>(
            xb, Wt_ff1 + (size_t)l * 262144, b_ff1 + (size_t)l * 1024, hid,
            S_TOTAL, 1024, 256);
        // out = LN2(out + hid @ Wff2 + b); xb, qb for next layer
        gemm_ln_kernel<1><<<LB, 256, 0, stream>>>(
            hid, Wt_ff2 + (size_t)l * 262144, b_ff2 + (size_t)l * 256,
            ln2_g + (size_t)l * 256, ln2_b + (size_t)l * 256, pos,
            out, xb, qb, S_TOTAL, 1024);
    }
}